// Round 11
// baseline (192.206 us; speedup 1.0000x reference)
//
#include <hip/hip_runtime.h>
#include <cmath>

#define NUM_POS 10
#define NEG 1000
#define COLS 1010          // NUM_POS + NEG
#define BATCH 4096
#define USERS 10001
#define ITEMS 10001
#define R_TOT (BATCH * NUM_POS)   // 40960
#define HSIZE (1 << 17)
#define GAMMA0 0.1f
#define EPSV 1e-10f

#define N_U 100020001LL            // USERS*ITEMS elements in u
// out[0]=loss, out[1..N_U]=u_new.  out4[k]=out[4k..4k+3]; full quads k=1..25004999
#define KMAX 25005000LL
#define CPY_QUADS (KMAX - 1)                    // 25004999
#define CPY_BLOCKS ((CPY_QUADS + 255) / 256)    // 97676
#define MEGA_BLOCKS (BATCH + CPY_BLOCKS)        // 101772
#define ROWS_SPAN (BATCH * 24)                  // 98304: rows blocks at bid%24==0
#define SCAT_BLOCKS (R_TOT / 256)               // 160

__device__ __forceinline__ unsigned hash_key(int k) {
    return (((unsigned)k * 2654435761u) >> 13) & (HSIZE - 1);
}

// ---- mega kernel: rows blocks interleaved 1-per-24 among copy blocks ----
__global__ void k_mega(const float* __restrict__ pred, const float* __restrict__ u,
                       float* __restrict__ out, float* __restrict__ rowM,
                       float* __restrict__ eRow, float* __restrict__ fRow,
                       float* __restrict__ mRow, int* __restrict__ hkey,
                       int* __restrict__ counter) {
    __shared__ float smem[1028];            // rows: 505 float2 (4040B); copy: 1028 floats
    int t = threadIdx.x;
    int bid = blockIdx.x;

    bool is_rows;
    int idx;                                // rows: b in [0,4096); copy: cidx in [0,97676)
    if (bid < ROWS_SPAN) {
        int q = bid / 24;
        is_rows = (bid - q * 24) == 0;
        idx = is_rows ? q : (bid - q - 1);
    } else {
        is_rows = false;
        idx = bid - BATCH;
    }

    if (is_rows) {
        // ---------------- rows path (R10 verbatim) ----------------
        int b = idx;
        float2* lrow = (float2*)smem;
        __shared__ float smn[4], smx[4], sh[8];
        const float2* row2 = (const float2*)(pred + (size_t)b * COLS);  // 8B-aligned
        float mn = INFINITY, mx = -INFINITY;
        for (int i = t; i < 505; i += 256) {
            float2 v = row2[i];
            lrow[i] = v;
            if (i < 5) mn = fminf(mn, fminf(v.x, v.y));   // pos 0..9
            else       mx = fmaxf(mx, fmaxf(v.x, v.y));   // neg 10..1009
        }
        // init hash slice: 64 ints (16 int4) per block; hval contiguous after hkey
        if (t < 16)
            ((int4*)hkey)[b * 16 + t] = make_int4(-1, -1, -1, -1);
        if (b == 0 && t == 16) *counter = 0;

        int lane = t & 63, wid = t >> 6;
        for (int off = 32; off; off >>= 1) {
            mn = fminf(mn, __shfl_down(mn, off));
            mx = fmaxf(mx, __shfl_down(mx, off));
        }
        if (lane == 0) { smn[wid] = mn; smx[wid] = mx; }
        __syncthreads();
        mx = fmaxf(fmaxf(smx[0], smx[1]), fmaxf(smx[2], smx[3]));   // row neg-max
        if (t == 0) {
            mn = fminf(fminf(smn[0], smn[1]), fminf(smn[2], smn[3]));
            rowM[b] = mx - mn;    // row's max margin
            mRow[b] = mx;
        }
        // pass 2 from LDS with local shift
        float e = 0.f, f = 0.f;
        for (int i = 5 + t; i < 505; i += 256) {
            float2 v = lrow[i];
            float w0 = expf(v.x - mx), w1 = expf(v.y - mx);
            e += w0 + w1;
            f += v.x * w0 + v.y * w1;
        }
        for (int off = 32; off; off >>= 1) { e += __shfl_down(e, off); f += __shfl_down(f, off); }
        if (lane == 0) { sh[wid] = e; sh[4 + wid] = f; }
        __syncthreads();
        if (t == 0) {
            eRow[b] = (sh[0] + sh[1]) + (sh[2] + sh[3]);
            fRow[b] = (sh[4] + sh[5]) + (sh[6] + sh[7]);
        }
    } else {
        // ---------------- copy path (R6/R10 verbatim) ----------------
        float* lds = smem;
        const float4* __restrict__ u4 = (const float4*)u;
        float4* __restrict__ o4 = (float4*)out;
        long long K0 = 1 + (long long)idx * 256;
        long long k = K0 + t;
        int nq = (int)((KMAX - K0 < 256) ? (KMAX - K0) : 256);

        if (t < nq)
            ((float4*)lds)[t] = u4[k - 1];        // aligned global load, aligned LDS write
        if (t == 0)
            ((float4*)lds)[nq] = u4[K0 + nq - 1]; // one extra quad per block
        __syncthreads();
        if (t < nq) {
            float x = lds[4 * t + 3], y = lds[4 * t + 4];
            float z = lds[4 * t + 5], w = lds[4 * t + 6];
            o4[k] = make_float4(x, y, z, w);      // aligned global store
        }
        if (idx == 0 && t == 0) {
            out[1] = u[0]; out[2] = u[1]; out[3] = u[2];
            out[100020000] = u[100019999];
            out[100020001] = u[100020000];
        }
    }
}

// ---- kernel B: global M (per-block reduce of rowM), emit meanexp/sumS/keys + insert ----
__global__ void k_emit(const float* __restrict__ pred, const float* __restrict__ rowM,
                       const float* __restrict__ eRow, const float* __restrict__ fRow,
                       const float* __restrict__ mRow, const int* __restrict__ user_id,
                       const int* __restrict__ item_id, float* __restrict__ meanexp,
                       float* __restrict__ sumS, int* __restrict__ keys,
                       int* __restrict__ hkey, int* __restrict__ hval) {
    float mx = -INFINITY;
    for (int i = threadIdx.x; i < BATCH; i += 256) mx = fmaxf(mx, rowM[i]);
    __shared__ float smx[4];
    int lane = threadIdx.x & 63, wid = threadIdx.x >> 6;
    for (int off = 32; off; off >>= 1) mx = fmaxf(mx, __shfl_down(mx, off));
    if (lane == 0) smx[wid] = mx;
    __syncthreads();
    float M = fmaxf(fmaxf(smx[0], smx[1]), fmaxf(smx[2], smx[3]));  // global max margin

    int r = blockIdx.x * 256 + threadIdx.x;        // < 40960
    int b = r / NUM_POS, p = r - b * NUM_POS;
    float pos = pred[(size_t)b * COLS + p];
    float scale = expf(mRow[b] - M);
    float E = eRow[b] * scale, F = fRow[b] * scale;
    float s = expf(-pos);
    meanexp[r] = s * E * (1.0f / NEG);
    sumS[r]    = s * (F - pos * E);
    int key = user_id[b] * ITEMS + item_id[r];
    keys[r] = key;
    unsigned sl = hash_key(key);
    while (true) {
        int old = atomicCAS(&hkey[sl], -1, key);
        if (old == -1 || old == key) { atomicMax(&hval[sl], r); break; }
        sl = (sl + 1) & (HSIZE - 1);
    }
}

// ---- scatter winners + loss partials + deterministic last-block final reduce ----
__global__ void k_scatter(const float* __restrict__ u_in, const float* __restrict__ meanexp,
                          const float* __restrict__ sumS, const int* __restrict__ keys,
                          const int* __restrict__ hkey, const int* __restrict__ hval,
                          float* __restrict__ u_out, float* __restrict__ partial,
                          int* __restrict__ counter, float* __restrict__ out0) {
    int r = blockIdx.x * 256 + threadIdx.x;
    int k = keys[r];
    unsigned s = hash_key(k);
    while (hkey[s] != k) s = (s + 1) & (HSIZE - 1);
    int win = hval[s];                        // last duplicate index wins
    float uval = u_in[(size_t)k];
    float nv = (1.0f - GAMMA0) * uval + GAMMA0 * meanexp[win];
    if (win == r) u_out[(size_t)k] = nv;
    float contrib = sumS[r] / (nv + EPSV);

    __shared__ float sh[4];
    __shared__ int amLast;
    int lane = threadIdx.x & 63, wid = threadIdx.x >> 6;
    for (int off = 32; off; off >>= 1) contrib += __shfl_down(contrib, off);
    if (lane == 0) sh[wid] = contrib;
    __syncthreads();
    if (threadIdx.x == 0) {
        partial[blockIdx.x] = (sh[0] + sh[1]) + (sh[2] + sh[3]);
        __threadfence();
        int prev = atomicAdd(counter, 1);
        amLast = (prev == SCAT_BLOCKS - 1);
    }
    __syncthreads();
    if (amLast) {
        __threadfence();
        const volatile float* vp = (const volatile float*)partial;
        float v = (threadIdx.x < SCAT_BLOCKS) ? vp[threadIdx.x] : 0.0f;
        for (int off = 32; off; off >>= 1) v += __shfl_down(v, off);
        __shared__ float s2[4];
        if (lane == 0) s2[wid] = v;
        __syncthreads();
        if (threadIdx.x == 0)
            out0[0] = ((s2[0] + s2[1]) + (s2[2] + s2[3])) * (1.0f / BATCH);
    }
}

extern "C" void kernel_launch(void* const* d_in, const int* in_sizes, int n_in,
                              void* d_out, int out_size, void* d_ws, size_t ws_size,
                              hipStream_t stream) {
    const float* pred    = (const float*)d_in[0];   // (4096, 1010)
    const float* u       = (const float*)d_in[1];   // (10001, 10001)
    const int*   user_id = (const int*)d_in[2];     // (4096,)
    const int*   item_id = (const int*)d_in[3];     // (4096, 10) flat

    float* out = (float*)d_out;     // [0]=loss, [1..]=u_new

    char* w = (char*)d_ws;
    int*   hkey    = (int*)w;    w += HSIZE * sizeof(int);
    int*   hval    = (int*)w;    w += HSIZE * sizeof(int);   // contiguous after hkey
    int*   counter = (int*)w;    w += 64;
    float* rowM    = (float*)w;  w += BATCH * sizeof(float);
    float* eRow    = (float*)w;  w += BATCH * sizeof(float);
    float* fRow    = (float*)w;  w += BATCH * sizeof(float);
    float* mRow    = (float*)w;  w += BATCH * sizeof(float);
    float* meanexp = (float*)w;  w += R_TOT * sizeof(float);
    float* sumS    = (float*)w;  w += R_TOT * sizeof(float);
    int*   keys    = (int*)w;    w += R_TOT * sizeof(int);
    float* partial = (float*)w;  w += 256 * sizeof(float);

    k_mega<<<MEGA_BLOCKS, 256, 0, stream>>>(pred, u, out, rowM, eRow, fRow, mRow,
                                            hkey, counter);
    k_emit<<<SCAT_BLOCKS, 256, 0, stream>>>(pred, rowM, eRow, fRow, mRow,
                                            user_id, item_id, meanexp, sumS, keys,
                                            hkey, hval);
    k_scatter<<<SCAT_BLOCKS, 256, 0, stream>>>(u, meanexp, sumS, keys, hkey, hval,
                                               out + 1, partial, counter, out);
}

// Round 12
// 168.750 us; speedup vs baseline: 1.1390x; 1.1390x over previous
//
#include <hip/hip_runtime.h>
#include <cmath>

#define NUM_POS 10
#define NEG 1000
#define COLS 1010          // NUM_POS + NEG
#define BATCH 4096
#define USERS 10001
#define ITEMS 10001
#define R_TOT (BATCH * NUM_POS)   // 40960
#define HSIZE (1 << 17)
#define GAMMA0 0.1f
#define EPSV 1e-10f

#define N_U 100020001LL            // USERS*ITEMS elements in u
// out[0]=loss, out[1..N_U]=u_new.  out4[k]=out[4k..4k+3]; full quads k=1..25004999
#define KMAX 25005000LL
#define CPY_QUADS (KMAX - 1)                    // 25004999
#define CPY_BLOCKS ((CPY_QUADS + 255) / 256)    // 97676
#define MEGA_BLOCKS (BATCH + CPY_BLOCKS)        // 101772
#define SCAT_BLOCKS (R_TOT / 256)               // 160

typedef float __attribute__((ext_vector_type(4))) f32x4;

__device__ __forceinline__ unsigned hash_key(int k) {
    return (((unsigned)k * 2654435761u) >> 13) & (HSIZE - 1);
}

// ---- mega kernel: blocks [0,BATCH) = rows path; [BATCH,...) = NT copy path ----
__global__ void k_mega(const float* __restrict__ pred, const float* __restrict__ u,
                       float* __restrict__ out, float* __restrict__ rowM,
                       float* __restrict__ eRow, float* __restrict__ fRow,
                       float* __restrict__ mRow, int* __restrict__ hkey,
                       int* __restrict__ counter) {
    __shared__ float smem[1028];            // rows: 505 float2 (4040B); copy: 1028 floats
    int t = threadIdx.x;

    if (blockIdx.x < BATCH) {
        // ---------------- rows path (R10 verbatim) ----------------
        int b = blockIdx.x;
        float2* lrow = (float2*)smem;
        __shared__ float smn[4], smx[4], sh[8];
        const float2* row2 = (const float2*)(pred + (size_t)b * COLS);  // 8B-aligned
        float mn = INFINITY, mx = -INFINITY;
        for (int i = t; i < 505; i += 256) {
            float2 v = row2[i];
            lrow[i] = v;
            if (i < 5) mn = fminf(mn, fminf(v.x, v.y));   // pos 0..9
            else       mx = fmaxf(mx, fmaxf(v.x, v.y));   // neg 10..1009
        }
        // init hash slice: 64 ints (16 int4) per block; hval contiguous after hkey
        if (t < 16)
            ((int4*)hkey)[b * 16 + t] = make_int4(-1, -1, -1, -1);
        if (b == 0 && t == 16) *counter = 0;

        int lane = t & 63, wid = t >> 6;
        for (int off = 32; off; off >>= 1) {
            mn = fminf(mn, __shfl_down(mn, off));
            mx = fmaxf(mx, __shfl_down(mx, off));
        }
        if (lane == 0) { smn[wid] = mn; smx[wid] = mx; }
        __syncthreads();
        mx = fmaxf(fmaxf(smx[0], smx[1]), fmaxf(smx[2], smx[3]));   // row neg-max
        if (t == 0) {
            mn = fminf(fminf(smn[0], smn[1]), fminf(smn[2], smn[3]));
            rowM[b] = mx - mn;    // row's max margin
            mRow[b] = mx;
        }
        // pass 2 from LDS with local shift
        float e = 0.f, f = 0.f;
        for (int i = 5 + t; i < 505; i += 256) {
            float2 v = lrow[i];
            float w0 = expf(v.x - mx), w1 = expf(v.y - mx);
            e += w0 + w1;
            f += v.x * w0 + v.y * w1;
        }
        for (int off = 32; off; off >>= 1) { e += __shfl_down(e, off); f += __shfl_down(f, off); }
        if (lane == 0) { sh[wid] = e; sh[4 + wid] = f; }
        __syncthreads();
        if (t == 0) {
            eRow[b] = (sh[0] + sh[1]) + (sh[2] + sh[3]);
            fRow[b] = (sh[4] + sh[5]) + (sh[6] + sh[7]);
        }
    } else {
        // -------- copy path (R6 structure + non-temporal load/store) --------
        float* lds = smem;
        const f32x4* __restrict__ u4 = (const f32x4*)u;
        f32x4* __restrict__ o4 = (f32x4*)out;
        long long K0 = 1 + (long long)(blockIdx.x - BATCH) * 256;
        long long k = K0 + t;
        int nq = (int)((KMAX - K0 < 256) ? (KMAX - K0) : 256);

        if (t < nq)
            ((f32x4*)lds)[t] = __builtin_nontemporal_load(&u4[k - 1]);
        if (t == 0)
            ((f32x4*)lds)[nq] = __builtin_nontemporal_load(&u4[K0 + nq - 1]);
        __syncthreads();
        if (t < nq) {
            f32x4 o;
            o.x = lds[4 * t + 3]; o.y = lds[4 * t + 4];
            o.z = lds[4 * t + 5]; o.w = lds[4 * t + 6];
            __builtin_nontemporal_store(o, &o4[k]);
        }
        if (blockIdx.x == BATCH && t == 0) {
            out[1] = u[0]; out[2] = u[1]; out[3] = u[2];
            out[100020000] = u[100019999];
            out[100020001] = u[100020000];
        }
    }
}

// ---- kernel B: global M (per-block reduce of rowM), emit meanexp/sumS/keys + insert ----
__global__ void k_emit(const float* __restrict__ pred, const float* __restrict__ rowM,
                       const float* __restrict__ eRow, const float* __restrict__ fRow,
                       const float* __restrict__ mRow, const int* __restrict__ user_id,
                       const int* __restrict__ item_id, float* __restrict__ meanexp,
                       float* __restrict__ sumS, int* __restrict__ keys,
                       int* __restrict__ hkey, int* __restrict__ hval) {
    float mx = -INFINITY;
    for (int i = threadIdx.x; i < BATCH; i += 256) mx = fmaxf(mx, rowM[i]);
    __shared__ float smx[4];
    int lane = threadIdx.x & 63, wid = threadIdx.x >> 6;
    for (int off = 32; off; off >>= 1) mx = fmaxf(mx, __shfl_down(mx, off));
    if (lane == 0) smx[wid] = mx;
    __syncthreads();
    float M = fmaxf(fmaxf(smx[0], smx[1]), fmaxf(smx[2], smx[3]));  // global max margin

    int r = blockIdx.x * 256 + threadIdx.x;        // < 40960
    int b = r / NUM_POS, p = r - b * NUM_POS;
    float pos = pred[(size_t)b * COLS + p];
    float scale = expf(mRow[b] - M);
    float E = eRow[b] * scale, F = fRow[b] * scale;
    float s = expf(-pos);
    meanexp[r] = s * E * (1.0f / NEG);
    sumS[r]    = s * (F - pos * E);
    int key = user_id[b] * ITEMS + item_id[r];
    keys[r] = key;
    unsigned sl = hash_key(key);
    while (true) {
        int old = atomicCAS(&hkey[sl], -1, key);
        if (old == -1 || old == key) { atomicMax(&hval[sl], r); break; }
        sl = (sl + 1) & (HSIZE - 1);
    }
}

// ---- scatter winners + loss partials + deterministic last-block final reduce ----
__global__ void k_scatter(const float* __restrict__ u_in, const float* __restrict__ meanexp,
                          const float* __restrict__ sumS, const int* __restrict__ keys,
                          const int* __restrict__ hkey, const int* __restrict__ hval,
                          float* __restrict__ u_out, float* __restrict__ partial,
                          int* __restrict__ counter, float* __restrict__ out0) {
    int r = blockIdx.x * 256 + threadIdx.x;
    int k = keys[r];
    unsigned s = hash_key(k);
    while (hkey[s] != k) s = (s + 1) & (HSIZE - 1);
    int win = hval[s];                        // last duplicate index wins
    float uval = u_in[(size_t)k];
    float nv = (1.0f - GAMMA0) * uval + GAMMA0 * meanexp[win];
    if (win == r) u_out[(size_t)k] = nv;
    float contrib = sumS[r] / (nv + EPSV);

    __shared__ float sh[4];
    __shared__ int amLast;
    int lane = threadIdx.x & 63, wid = threadIdx.x >> 6;
    for (int off = 32; off; off >>= 1) contrib += __shfl_down(contrib, off);
    if (lane == 0) sh[wid] = contrib;
    __syncthreads();
    if (threadIdx.x == 0) {
        partial[blockIdx.x] = (sh[0] + sh[1]) + (sh[2] + sh[3]);
        __threadfence();
        int prev = atomicAdd(counter, 1);
        amLast = (prev == SCAT_BLOCKS - 1);
    }
    __syncthreads();
    if (amLast) {
        __threadfence();
        const volatile float* vp = (const volatile float*)partial;
        float v = (threadIdx.x < SCAT_BLOCKS) ? vp[threadIdx.x] : 0.0f;
        for (int off = 32; off; off >>= 1) v += __shfl_down(v, off);
        __shared__ float s2[4];
        if (lane == 0) s2[wid] = v;
        __syncthreads();
        if (threadIdx.x == 0)
            out0[0] = ((s2[0] + s2[1]) + (s2[2] + s2[3])) * (1.0f / BATCH);
    }
}

extern "C" void kernel_launch(void* const* d_in, const int* in_sizes, int n_in,
                              void* d_out, int out_size, void* d_ws, size_t ws_size,
                              hipStream_t stream) {
    const float* pred    = (const float*)d_in[0];   // (4096, 1010)
    const float* u       = (const float*)d_in[1];   // (10001, 10001)
    const int*   user_id = (const int*)d_in[2];     // (4096,)
    const int*   item_id = (const int*)d_in[3];     // (4096, 10) flat

    float* out = (float*)d_out;     // [0]=loss, [1..]=u_new

    char* w = (char*)d_ws;
    int*   hkey    = (int*)w;    w += HSIZE * sizeof(int);
    int*   hval    = (int*)w;    w += HSIZE * sizeof(int);   // contiguous after hkey
    int*   counter = (int*)w;    w += 64;
    float* rowM    = (float*)w;  w += BATCH * sizeof(float);
    float* eRow    = (float*)w;  w += BATCH * sizeof(float);
    float* fRow    = (float*)w;  w += BATCH * sizeof(float);
    float* mRow    = (float*)w;  w += BATCH * sizeof(float);
    float* meanexp = (float*)w;  w += R_TOT * sizeof(float);
    float* sumS    = (float*)w;  w += R_TOT * sizeof(float);
    int*   keys    = (int*)w;    w += R_TOT * sizeof(int);
    float* partial = (float*)w;  w += 256 * sizeof(float);

    k_mega<<<MEGA_BLOCKS, 256, 0, stream>>>(pred, u, out, rowM, eRow, fRow, mRow,
                                            hkey, counter);
    k_emit<<<SCAT_BLOCKS, 256, 0, stream>>>(pred, rowM, eRow, fRow, mRow,
                                            user_id, item_id, meanexp, sumS, keys,
                                            hkey, hval);
    k_scatter<<<SCAT_BLOCKS, 256, 0, stream>>>(u, meanexp, sumS, keys, hkey, hval,
                                               out + 1, partial, counter, out);
}